// Round 3
// baseline (665.398 us; speedup 1.0000x reference)
//
#include <hip/hip_runtime.h>

#define N_NODES 50000
#define E_EDGES 1600000
#define FN 8
#define FE 8
#define HID 16
#define IH 10
#define NB_SCAN 196   // ceil(50000/256)

// ---------------- workspace layout ----------------
// ints:   cnt[N] @0, offset[N+1] @50048, rank[E] @100096, bsum[256] @1700096,
//         bbase[256] @1700352  -> I_TOTAL 1700608
// floats: h[N*16] @0, h2[N*10] @800000, msg[E*16] @1300000
#define I_CNT   0
#define I_OFF   50048
#define I_RANK  100096
#define I_BSUM  1700096
#define I_BBASE 1700352
#define I_TOTAL 1700608
#define F_H     0
#define F_H2    800000
#define F_MSG   1300000
#define F_TOTAL 26900000
#define WS_NEED ((size_t)I_TOTAL*4 + (size_t)F_TOTAL*4)

// ================= CSR build =================
__global__ __launch_bounds__(256) void count_rank_k(
    const int* __restrict__ ei, int* __restrict__ cnt, int* __restrict__ rank)
{
    int e = blockIdx.x * 256 + threadIdx.x;
    if (e >= E_EDGES) return;
    int dst = ei[E_EDGES + e];
    rank[e] = atomicAdd(&cnt[dst], 1);
}

__global__ __launch_bounds__(256) void blocksum_k(
    const int* __restrict__ cnt, int* __restrict__ bsum)
{
    __shared__ int sh[256];
    int t = threadIdx.x;
    int idx = blockIdx.x * 256 + t;
    sh[t] = (idx < N_NODES) ? cnt[idx] : 0;
    __syncthreads();
#pragma unroll
    for (int d = 128; d > 0; d >>= 1) {
        if (t < d) sh[t] += sh[t + d];
        __syncthreads();
    }
    if (t == 0) bsum[blockIdx.x] = sh[0];
}

__global__ __launch_bounds__(256) void scan_bsums_k(
    const int* __restrict__ bsum, int* __restrict__ bbase)
{
    __shared__ int sh[256];
    int t = threadIdx.x;
    int v = (t < NB_SCAN) ? bsum[t] : 0;
    sh[t] = v;
    __syncthreads();
#pragma unroll
    for (int d = 1; d < 256; d <<= 1) {
        int u = (t >= d) ? sh[t - d] : 0;
        __syncthreads();
        sh[t] += u;
        __syncthreads();
    }
    if (t < NB_SCAN) bbase[t] = sh[t] - v;   // exclusive
}

__global__ __launch_bounds__(256) void offsets_k(
    const int* __restrict__ cnt, const int* __restrict__ bbase,
    int* __restrict__ offset)
{
    __shared__ int sh[256];
    int t = threadIdx.x;
    int b = blockIdx.x;
    int idx = b * 256 + t;
    int v = (idx < N_NODES) ? cnt[idx] : 0;
    sh[t] = v;
    __syncthreads();
#pragma unroll
    for (int d = 1; d < 256; d <<= 1) {
        int u = (t >= d) ? sh[t - d] : 0;
        __syncthreads();
        sh[t] += u;
        __syncthreads();
    }
    int incl = sh[t];
    int base = bbase[b];
    if (idx < N_NODES) offset[idx] = base + incl - v;
    if (idx == N_NODES - 1) offset[N_NODES] = base + incl;
}

// ================= per-edge helpers =================
__device__ __forceinline__ void load8(const float* __restrict__ p, float v[8]) {
    const float4* q = reinterpret_cast<const float4*>(p);
    float4 a = q[0], b = q[1];
    v[0]=a.x; v[1]=a.y; v[2]=a.z; v[3]=a.w;
    v[4]=b.x; v[5]=b.y; v[6]=b.z; v[7]=b.w;
}

__device__ __forceinline__ void edge_mlp(
    const float eav[FE], const float* __restrict__ w1,
    const float* __restrict__ b1, float u[IH])
{
#pragma unroll
    for (int h = 0; h < IH; ++h) {
        float s = b1[h];
#pragma unroll
        for (int k = 0; k < FE; ++k) s = fmaf(eav[k], w1[k*IH + h], s);
        u[h] = fmaxf(s, 0.f);
    }
}

// ================= conv0: 2 edges/thread, scatter to sorted slots =================
__global__ __launch_bounds__(256) void conv0_scatter_k(
    const float* __restrict__ x, const float* __restrict__ ea,
    const int* __restrict__ ei,
    const float* __restrict__ w1, const float* __restrict__ b1,
    const float* __restrict__ w2, const float* __restrict__ b2,
    const int* __restrict__ offset, const int* __restrict__ rank,
    float* __restrict__ msgbuf)          // [E][16]
{
    int gid = blockIdx.x * 256 + threadIdx.x;   // grid sized exactly E/2
    int e0 = gid * 2;
    int2 srcs  = *reinterpret_cast<const int2*>(ei + e0);
    int2 dsts  = *reinterpret_cast<const int2*>(ei + E_EDGES + e0);
    int2 ranks = *reinterpret_cast<const int2*>(rank + e0);

    float eav[2][FE];
    load8(ea + (size_t)e0 * FE,       eav[0]);
    load8(ea + (size_t)e0 * FE + FE,  eav[1]);
    float xv[2][FN];
    load8(x + (size_t)srcs.x * FN, xv[0]);
    load8(x + (size_t)srcs.y * FN, xv[1]);
    int pos0 = offset[dsts.x] + ranks.x;
    int pos1 = offset[dsts.y] + ranks.y;

#pragma unroll
    for (int ed = 0; ed < 2; ++ed) {
        float u[IH];
        edge_mlp(eav[ed], w1, b1, u);
        float msg[HID];
#pragma unroll
        for (int o = 0; o < HID; ++o) msg[o] = 0.f;
#pragma unroll
        for (int i = 0; i < FN; ++i) {
            float xi = xv[ed][i];
#pragma unroll
            for (int o = 0; o < HID; ++o) {
                float t = b2[i*HID + o];
#pragma unroll
                for (int h = 0; h < IH; ++h)
                    t = fmaf(u[h], w2[h*(FN*HID) + i*HID + o], t);
                msg[o] = fmaf(xi, t, msg[o]);
            }
        }
        size_t pos = (size_t)(ed == 0 ? pos0 : pos1) * HID;
        float4* mp = reinterpret_cast<float4*>(msgbuf + pos);
        mp[0] = make_float4(msg[0],  msg[1],  msg[2],  msg[3]);
        mp[1] = make_float4(msg[4],  msg[5],  msg[6],  msg[7]);
        mp[2] = make_float4(msg[8],  msg[9],  msg[10], msg[11]);
        mp[3] = make_float4(msg[12], msg[13], msg[14], msg[15]);
    }
}

// ================= node0: segmented reduce + root + relu =================
__global__ __launch_bounds__(256) void node0_red_k(
    const float* __restrict__ x, const float* __restrict__ msgbuf,
    const int* __restrict__ offset,
    const float* __restrict__ root, const float* __restrict__ bias,
    float* __restrict__ h)
{
    int idx = blockIdx.x * 256 + threadIdx.x;
    if (idx >= N_NODES * HID) return;
    int n = idx >> 4;
    int o = idx & 15;
    int beg = offset[n], end = offset[n + 1];
    float s = bias[o];
    for (int j = beg; j < end; ++j) s += msgbuf[(size_t)j * HID + o];
    const float* xr = x + (size_t)n * FN;
#pragma unroll
    for (int i = 0; i < FN; ++i) s = fmaf(xr[i], root[i*HID + o], s);
    h[idx] = fmaxf(s, 0.f);
}

// ================= conv1: 2 edges/thread, scatter =================
__global__ __launch_bounds__(256) void conv1_scatter_k(
    const float* __restrict__ hin, const float* __restrict__ ea,
    const int* __restrict__ ei,
    const float* __restrict__ w1, const float* __restrict__ b1,
    const float* __restrict__ w2, const float* __restrict__ b2,
    const int* __restrict__ offset, const int* __restrict__ rank,
    float* __restrict__ msgbuf)          // [E][10]
{
    int gid = blockIdx.x * 256 + threadIdx.x;
    int e0 = gid * 2;
    int2 srcs  = *reinterpret_cast<const int2*>(ei + e0);
    int2 dsts  = *reinterpret_cast<const int2*>(ei + E_EDGES + e0);
    int2 ranks = *reinterpret_cast<const int2*>(rank + e0);

    float eav[2][FE];
    load8(ea + (size_t)e0 * FE,      eav[0]);
    load8(ea + (size_t)e0 * FE + FE, eav[1]);
    int pos0 = offset[dsts.x] + ranks.x;
    int pos1 = offset[dsts.y] + ranks.y;

#pragma unroll
    for (int ed = 0; ed < 2; ++ed) {
        int src = (ed == 0) ? srcs.x : srcs.y;
        float hv[HID];
        {
            const float4* p = reinterpret_cast<const float4*>(hin + (size_t)src * HID);
            float4 a = p[0], b = p[1], c = p[2], d = p[3];
            hv[0]=a.x;  hv[1]=a.y;  hv[2]=a.z;   hv[3]=a.w;
            hv[4]=b.x;  hv[5]=b.y;  hv[6]=b.z;   hv[7]=b.w;
            hv[8]=c.x;  hv[9]=c.y;  hv[10]=c.z;  hv[11]=c.w;
            hv[12]=d.x; hv[13]=d.y; hv[14]=d.z;  hv[15]=d.w;
        }
        float u[IH];
        edge_mlp(eav[ed], w1, b1, u);
        float msg[IH];
#pragma unroll
        for (int o = 0; o < IH; ++o) msg[o] = 0.f;
#pragma unroll
        for (int i = 0; i < HID; ++i) {
            float hi = hv[i];
#pragma unroll
            for (int o = 0; o < IH; ++o) {
                float t = b2[i*IH + o];
#pragma unroll
                for (int h = 0; h < IH; ++h)
                    t = fmaf(u[h], w2[h*(HID*IH) + i*IH + o], t);
                msg[o] = fmaf(hi, t, msg[o]);
            }
        }
        size_t pos = (size_t)(ed == 0 ? pos0 : pos1) * IH;
        float2* mp = reinterpret_cast<float2*>(msgbuf + pos);
        mp[0] = make_float2(msg[0], msg[1]);
        mp[1] = make_float2(msg[2], msg[3]);
        mp[2] = make_float2(msg[4], msg[5]);
        mp[3] = make_float2(msg[6], msg[7]);
        mp[4] = make_float2(msg[8], msg[9]);
    }
}

// ================= node1: segmented reduce + root + relu =================
__global__ __launch_bounds__(256) void node1_red_k(
    const float* __restrict__ hin, const float* __restrict__ msgbuf,
    const int* __restrict__ offset,
    const float* __restrict__ root, const float* __restrict__ bias,
    float* __restrict__ h2)
{
    int idx = blockIdx.x * 256 + threadIdx.x;
    if (idx >= N_NODES * IH) return;
    int n = idx / IH;
    int o = idx - n * IH;
    int beg = offset[n], end = offset[n + 1];
    float s = bias[o];
    for (int j = beg; j < end; ++j) s += msgbuf[(size_t)j * IH + o];
    const float* hr = hin + (size_t)n * HID;
#pragma unroll
    for (int i = 0; i < HID; ++i) s = fmaf(hr[i], root[i*IH + o], s);
    h2[idx] = fmaxf(s, 0.f);
}

// ================= edge predictor: 2 edges/thread =================
__global__ __launch_bounds__(256) void edge_pred_k(
    const float* __restrict__ h2, const float* __restrict__ ea,
    const int* __restrict__ ei,
    const float* __restrict__ w1, const float* __restrict__ b1,
    const float* __restrict__ w2, const float* __restrict__ b2,
    float* __restrict__ out)
{
    int gid = blockIdx.x * 256 + threadIdx.x;
    int e0 = gid * 2;
    int2 srcs = *reinterpret_cast<const int2*>(ei + e0);

    float eav[2][FE];
    load8(ea + (size_t)e0 * FE,      eav[0]);
    load8(ea + (size_t)e0 * FE + FE, eav[1]);

    float res[2];
#pragma unroll
    for (int ed = 0; ed < 2; ++ed) {
        int src = (ed == 0) ? srcs.x : srcs.y;
        float hv[IH];
        {
            const float2* p = reinterpret_cast<const float2*>(h2 + (size_t)src * IH);
            float2 a = p[0], b = p[1], c = p[2], d = p[3], f = p[4];
            hv[0]=a.x; hv[1]=a.y; hv[2]=b.x; hv[3]=b.y; hv[4]=c.x;
            hv[5]=c.y; hv[6]=d.x; hv[7]=d.y; hv[8]=f.x; hv[9]=f.y;
        }
        float score = b2[0];
#pragma unroll
        for (int j = 0; j < IH; ++j) {
            float s = b1[j];
#pragma unroll
            for (int k = 0; k < FE; ++k) s = fmaf(eav[ed][k], w1[k*IH + j], s);
#pragma unroll
            for (int k = 0; k < IH; ++k) s = fmaf(hv[k], w1[(FE + k)*IH + j], s);
            s = fmaxf(s, 0.f);
            score = fmaf(s, w2[j], score);
        }
        res[ed] = score;
    }
    *reinterpret_cast<float2*>(out + e0) = make_float2(res[0], res[1]);
}

// ================= fallback (atomic) path =================
__global__ __launch_bounds__(256) void conv0_edge_k(
    const float* __restrict__ x, const float* __restrict__ ea,
    const int* __restrict__ ei,
    const float* __restrict__ w1, const float* __restrict__ b1,
    const float* __restrict__ w2, const float* __restrict__ b2,
    float* __restrict__ agg)
{
    int e = blockIdx.x * 256 + threadIdx.x;
    if (e >= E_EDGES) return;
    int src = ei[e];
    int dst = ei[E_EDGES + e];
    float eav[FE];
    load8(ea + (size_t)e * FE, eav);
    float u[IH];
    edge_mlp(eav, w1, b1, u);
    float xv[FN];
    load8(x + (size_t)src * FN, xv);
    float msg[HID];
#pragma unroll
    for (int o = 0; o < HID; ++o) msg[o] = 0.f;
#pragma unroll
    for (int i = 0; i < FN; ++i) {
        float xi = xv[i];
#pragma unroll
        for (int o = 0; o < HID; ++o) {
            float t = b2[i*HID + o];
#pragma unroll
            for (int h = 0; h < IH; ++h)
                t = fmaf(u[h], w2[h*(FN*HID) + i*HID + o], t);
            msg[o] = fmaf(xi, t, msg[o]);
        }
    }
    float* ap = agg + (size_t)dst * HID;
#pragma unroll
    for (int o = 0; o < HID; ++o) atomicAdd(ap + o, msg[o]);
}

__global__ __launch_bounds__(256) void node0_k(
    const float* __restrict__ x, const float* __restrict__ agg,
    const float* __restrict__ root, const float* __restrict__ bias,
    float* __restrict__ h)
{
    int idx = blockIdx.x * 256 + threadIdx.x;
    if (idx >= N_NODES * HID) return;
    int n = idx >> 4;
    int o = idx & 15;
    float s = agg[idx] + bias[o];
    const float* xr = x + (size_t)n * FN;
#pragma unroll
    for (int i = 0; i < FN; ++i) s = fmaf(xr[i], root[i*HID + o], s);
    h[idx] = fmaxf(s, 0.f);
}

__global__ __launch_bounds__(256) void conv1_edge_k(
    const float* __restrict__ hin, const float* __restrict__ ea,
    const int* __restrict__ ei,
    const float* __restrict__ w1, const float* __restrict__ b1,
    const float* __restrict__ w2, const float* __restrict__ b2,
    float* __restrict__ agg)
{
    int e = blockIdx.x * 256 + threadIdx.x;
    if (e >= E_EDGES) return;
    int src = ei[e];
    int dst = ei[E_EDGES + e];
    float eav[FE];
    load8(ea + (size_t)e * FE, eav);
    float u[IH];
    edge_mlp(eav, w1, b1, u);
    float hv[HID];
    {
        const float4* p = reinterpret_cast<const float4*>(hin + (size_t)src * HID);
        float4 a = p[0], b = p[1], c = p[2], d = p[3];
        hv[0]=a.x;  hv[1]=a.y;  hv[2]=a.z;   hv[3]=a.w;
        hv[4]=b.x;  hv[5]=b.y;  hv[6]=b.z;   hv[7]=b.w;
        hv[8]=c.x;  hv[9]=c.y;  hv[10]=c.z;  hv[11]=c.w;
        hv[12]=d.x; hv[13]=d.y; hv[14]=d.z;  hv[15]=d.w;
    }
    float msg[IH];
#pragma unroll
    for (int o = 0; o < IH; ++o) msg[o] = 0.f;
#pragma unroll
    for (int i = 0; i < HID; ++i) {
        float hi = hv[i];
#pragma unroll
        for (int o = 0; o < IH; ++o) {
            float t = b2[i*IH + o];
#pragma unroll
            for (int h = 0; h < IH; ++h)
                t = fmaf(u[h], w2[h*(HID*IH) + i*IH + o], t);
            msg[o] = fmaf(hi, t, msg[o]);
        }
    }
    float* ap = agg + (size_t)dst * IH;
#pragma unroll
    for (int o = 0; o < IH; ++o) atomicAdd(ap + o, msg[o]);
}

__global__ __launch_bounds__(256) void node1_k(
    const float* __restrict__ hin, const float* __restrict__ agg,
    const float* __restrict__ root, const float* __restrict__ bias,
    float* __restrict__ h2)
{
    int idx = blockIdx.x * 256 + threadIdx.x;
    if (idx >= N_NODES * IH) return;
    int n = idx / IH;
    int o = idx - n * IH;
    float s = agg[idx] + bias[o];
    const float* hr = hin + (size_t)n * HID;
#pragma unroll
    for (int i = 0; i < HID; ++i) s = fmaf(hr[i], root[i*IH + o], s);
    h2[idx] = fmaxf(s, 0.f);
}

__global__ __launch_bounds__(256) void edge_pred1_k(
    const float* __restrict__ h2, const float* __restrict__ ea,
    const int* __restrict__ ei,
    const float* __restrict__ w1, const float* __restrict__ b1,
    const float* __restrict__ w2, const float* __restrict__ b2,
    float* __restrict__ out)
{
    int e = blockIdx.x * 256 + threadIdx.x;
    if (e >= E_EDGES) return;
    int src = ei[e];
    float eav[FE];
    load8(ea + (size_t)e * FE, eav);
    float hv[IH];
    {
        const float2* p = reinterpret_cast<const float2*>(h2 + (size_t)src * IH);
        float2 a = p[0], b = p[1], c = p[2], d = p[3], f = p[4];
        hv[0]=a.x; hv[1]=a.y; hv[2]=b.x; hv[3]=b.y; hv[4]=c.x;
        hv[5]=c.y; hv[6]=d.x; hv[7]=d.y; hv[8]=f.x; hv[9]=f.y;
    }
    float score = b2[0];
#pragma unroll
    for (int j = 0; j < IH; ++j) {
        float s = b1[j];
#pragma unroll
        for (int k = 0; k < FE; ++k) s = fmaf(eav[k], w1[k*IH + j], s);
#pragma unroll
        for (int k = 0; k < IH; ++k) s = fmaf(hv[k], w1[(FE + k)*IH + j], s);
        s = fmaxf(s, 0.f);
        score = fmaf(s, w2[j], score);
    }
    out[e] = score;
}

extern "C" void kernel_launch(void* const* d_in, const int* in_sizes, int n_in,
                              void* d_out, int out_size, void* d_ws, size_t ws_size,
                              hipStream_t stream) {
    const float* x       = (const float*)d_in[0];
    const float* ea      = (const float*)d_in[1];
    const int*   ei      = (const int*)  d_in[2];
    const float* c0_w1   = (const float*)d_in[3];
    const float* c0_b1   = (const float*)d_in[4];
    const float* c0_w2   = (const float*)d_in[5];
    const float* c0_b2   = (const float*)d_in[6];
    const float* c0_root = (const float*)d_in[7];
    const float* c0_bias = (const float*)d_in[8];
    const float* c1_w1   = (const float*)d_in[9];
    const float* c1_b1   = (const float*)d_in[10];
    const float* c1_w2   = (const float*)d_in[11];
    const float* c1_b2   = (const float*)d_in[12];
    const float* c1_root = (const float*)d_in[13];
    const float* c1_bias = (const float*)d_in[14];
    const float* ep_w1   = (const float*)d_in[15];
    const float* ep_b1   = (const float*)d_in[16];
    const float* ep_w2   = (const float*)d_in[17];
    const float* ep_b2   = (const float*)d_in[18];
    float* out = (float*)d_out;

    int eb  = (E_EDGES + 255) / 256;
    int eb2 = (E_EDGES / 2 + 255) / 256;   // 3125, exact

    if (ws_size >= WS_NEED) {
        int*   wi     = (int*)d_ws;
        int*   cnt    = wi + I_CNT;
        int*   offset = wi + I_OFF;
        int*   rank   = wi + I_RANK;
        int*   bsum   = wi + I_BSUM;
        int*   bbase  = wi + I_BBASE;
        float* wf     = (float*)(wi + I_TOTAL);
        float* h      = wf + F_H;
        float* h2     = wf + F_H2;
        float* msg    = wf + F_MSG;

        hipMemsetAsync(cnt, 0, N_NODES * sizeof(int), stream);
        count_rank_k<<<eb, 256, 0, stream>>>(ei, cnt, rank);
        blocksum_k<<<NB_SCAN, 256, 0, stream>>>(cnt, bsum);
        scan_bsums_k<<<1, 256, 0, stream>>>(bsum, bbase);
        offsets_k<<<NB_SCAN, 256, 0, stream>>>(cnt, bbase, offset);

        conv0_scatter_k<<<eb2, 256, 0, stream>>>(x, ea, ei, c0_w1, c0_b1, c0_w2, c0_b2,
                                                 offset, rank, msg);
        node0_red_k<<<(N_NODES*HID + 255)/256, 256, 0, stream>>>(x, msg, offset,
                                                                 c0_root, c0_bias, h);
        conv1_scatter_k<<<eb2, 256, 0, stream>>>(h, ea, ei, c1_w1, c1_b1, c1_w2, c1_b2,
                                                 offset, rank, msg);
        node1_red_k<<<(N_NODES*IH + 255)/256, 256, 0, stream>>>(h, msg, offset,
                                                                c1_root, c1_bias, h2);
        edge_pred_k<<<eb2, 256, 0, stream>>>(h2, ea, ei, ep_w1, ep_b1, ep_w2, ep_b2, out);
    } else {
        float* ws   = (float*)d_ws;
        float* agg0 = ws;
        float* agg1 = ws + 800000;
        float* h    = ws + 1300000;
        float* h2   = ws + 2100000;
        hipMemsetAsync(d_ws, 0, 1300000 * sizeof(float), stream);
        conv0_edge_k<<<eb, 256, 0, stream>>>(x, ea, ei, c0_w1, c0_b1, c0_w2, c0_b2, agg0);
        node0_k<<<(N_NODES*HID + 255)/256, 256, 0, stream>>>(x, agg0, c0_root, c0_bias, h);
        conv1_edge_k<<<eb, 256, 0, stream>>>(h, ea, ei, c1_w1, c1_b1, c1_w2, c1_b2, agg1);
        node1_k<<<(N_NODES*IH + 255)/256, 256, 0, stream>>>(h, agg1, c1_root, c1_bias, h2);
        edge_pred1_k<<<eb, 256, 0, stream>>>(h2, ea, ei, ep_w1, ep_b1, ep_w2, ep_b2, out);
    }
}

// Round 4
// 303.347 us; speedup vs baseline: 2.1935x; 2.1935x over previous
//
#include <hip/hip_runtime.h>

#define N_NODES 50000
#define E_EDGES 1600000
#define FN 8
#define FE 8
#define HID 16
#define IH 10
#define NB_SCAN 196   // ceil(50000/256)

// ---------------- workspace layout ----------------
#define I_CNT   0
#define I_OFF   50048
#define I_RANK  100096
#define I_BSUM  1700096
#define I_BBASE 1700352
#define I_TOTAL 1700608
#define F_H     0
#define F_H2    800000
#define F_MSG   1300000
#define F_TOTAL 26900000
#define WS_NEED ((size_t)I_TOTAL*4 + (size_t)F_TOTAL*4)

// ================= CSR build =================
__global__ __launch_bounds__(256) void count_rank_k(
    const int* __restrict__ ei, int* __restrict__ cnt, int* __restrict__ rank)
{
    int e = blockIdx.x * 256 + threadIdx.x;
    if (e >= E_EDGES) return;
    int dst = ei[E_EDGES + e];
    rank[e] = atomicAdd(&cnt[dst], 1);
}

__global__ __launch_bounds__(256) void blocksum_k(
    const int* __restrict__ cnt, int* __restrict__ bsum)
{
    __shared__ int sh[256];
    int t = threadIdx.x;
    int idx = blockIdx.x * 256 + t;
    sh[t] = (idx < N_NODES) ? cnt[idx] : 0;
    __syncthreads();
#pragma unroll
    for (int d = 128; d > 0; d >>= 1) {
        if (t < d) sh[t] += sh[t + d];
        __syncthreads();
    }
    if (t == 0) bsum[blockIdx.x] = sh[0];
}

__global__ __launch_bounds__(256) void scan_bsums_k(
    const int* __restrict__ bsum, int* __restrict__ bbase)
{
    __shared__ int sh[256];
    int t = threadIdx.x;
    int v = (t < NB_SCAN) ? bsum[t] : 0;
    sh[t] = v;
    __syncthreads();
#pragma unroll
    for (int d = 1; d < 256; d <<= 1) {
        int u = (t >= d) ? sh[t - d] : 0;
        __syncthreads();
        sh[t] += u;
        __syncthreads();
    }
    if (t < NB_SCAN) bbase[t] = sh[t] - v;   // exclusive
}

__global__ __launch_bounds__(256) void offsets_k(
    const int* __restrict__ cnt, const int* __restrict__ bbase,
    int* __restrict__ offset)
{
    __shared__ int sh[256];
    int t = threadIdx.x;
    int b = blockIdx.x;
    int idx = b * 256 + t;
    int v = (idx < N_NODES) ? cnt[idx] : 0;
    sh[t] = v;
    __syncthreads();
#pragma unroll
    for (int d = 1; d < 256; d <<= 1) {
        int u = (t >= d) ? sh[t - d] : 0;
        __syncthreads();
        sh[t] += u;
        __syncthreads();
    }
    int incl = sh[t];
    int base = bbase[b];
    if (idx < N_NODES) offset[idx] = base + incl - v;
    if (idx == N_NODES - 1) offset[N_NODES] = base + incl;
}

// ================= per-edge helpers =================
__device__ __forceinline__ void load8(const float* __restrict__ p, float v[8]) {
    const float4* q = reinterpret_cast<const float4*>(p);
    float4 a = q[0], b = q[1];
    v[0]=a.x; v[1]=a.y; v[2]=a.z; v[3]=a.w;
    v[4]=b.x; v[5]=b.y; v[6]=b.z; v[7]=b.w;
}

__device__ __forceinline__ void edge_mlp(
    const float eav[FE], const float* __restrict__ w1,
    const float* __restrict__ b1, float u[IH])
{
#pragma unroll
    for (int h = 0; h < IH; ++h) {
        float s = b1[h];
#pragma unroll
        for (int k = 0; k < FE; ++k) s = fmaf(eav[k], w1[k*IH + h], s);
        u[h] = fmaxf(s, 0.f);
    }
}

// ================= conv0: 1 edge/thread, scatter to sorted slot =================
__global__ __launch_bounds__(256) void conv0_scatter_k(
    const float* __restrict__ x, const float* __restrict__ ea,
    const int* __restrict__ ei,
    const float* __restrict__ w1, const float* __restrict__ b1,
    const float* __restrict__ w2, const float* __restrict__ b2,
    const int* __restrict__ offset, const int* __restrict__ rank,
    float* __restrict__ msgbuf)          // [E][16]
{
    int e = blockIdx.x * 256 + threadIdx.x;
    if (e >= E_EDGES) return;
    int src = ei[e];
    int dst = ei[E_EDGES + e];

    float eav[FE];
    load8(ea + (size_t)e * FE, eav);
    float u[IH];
    edge_mlp(eav, w1, b1, u);
    float xv[FN];
    load8(x + (size_t)src * FN, xv);

    float msg[HID];
#pragma unroll
    for (int o = 0; o < HID; ++o) msg[o] = 0.f;
#pragma unroll
    for (int i = 0; i < FN; ++i) {
        float xi = xv[i];
#pragma unroll
        for (int o = 0; o < HID; ++o) {
            float t = b2[i*HID + o];
#pragma unroll
            for (int h = 0; h < IH; ++h)
                t = fmaf(u[h], w2[h*(FN*HID) + i*HID + o], t);
            msg[o] = fmaf(xi, t, msg[o]);
        }
    }
    size_t pos = (size_t)(offset[dst] + rank[e]) * HID;
    float4* mp = reinterpret_cast<float4*>(msgbuf + pos);
    mp[0] = make_float4(msg[0],  msg[1],  msg[2],  msg[3]);
    mp[1] = make_float4(msg[4],  msg[5],  msg[6],  msg[7]);
    mp[2] = make_float4(msg[8],  msg[9],  msg[10], msg[11]);
    mp[3] = make_float4(msg[12], msg[13], msg[14], msg[15]);
}

// ================= node0: segmented reduce + root + relu =================
__global__ __launch_bounds__(256) void node0_red_k(
    const float* __restrict__ x, const float* __restrict__ msgbuf,
    const int* __restrict__ offset,
    const float* __restrict__ root, const float* __restrict__ bias,
    float* __restrict__ h)
{
    int idx = blockIdx.x * 256 + threadIdx.x;
    if (idx >= N_NODES * HID) return;
    int n = idx >> 4;
    int o = idx & 15;
    int beg = offset[n], end = offset[n + 1];
    float s = bias[o];
    for (int j = beg; j < end; ++j) s += msgbuf[(size_t)j * HID + o];
    const float* xr = x + (size_t)n * FN;
#pragma unroll
    for (int i = 0; i < FN; ++i) s = fmaf(xr[i], root[i*HID + o], s);
    h[idx] = fmaxf(s, 0.f);
}

// ================= conv1: 1 edge/thread, scatter =================
__global__ __launch_bounds__(256) void conv1_scatter_k(
    const float* __restrict__ hin, const float* __restrict__ ea,
    const int* __restrict__ ei,
    const float* __restrict__ w1, const float* __restrict__ b1,
    const float* __restrict__ w2, const float* __restrict__ b2,
    const int* __restrict__ offset, const int* __restrict__ rank,
    float* __restrict__ msgbuf)          // [E][10]
{
    int e = blockIdx.x * 256 + threadIdx.x;
    if (e >= E_EDGES) return;
    int src = ei[e];
    int dst = ei[E_EDGES + e];

    float eav[FE];
    load8(ea + (size_t)e * FE, eav);
    float u[IH];
    edge_mlp(eav, w1, b1, u);
    float hv[HID];
    {
        const float4* p = reinterpret_cast<const float4*>(hin + (size_t)src * HID);
        float4 a = p[0], b = p[1], c = p[2], d = p[3];
        hv[0]=a.x;  hv[1]=a.y;  hv[2]=a.z;   hv[3]=a.w;
        hv[4]=b.x;  hv[5]=b.y;  hv[6]=b.z;   hv[7]=b.w;
        hv[8]=c.x;  hv[9]=c.y;  hv[10]=c.z;  hv[11]=c.w;
        hv[12]=d.x; hv[13]=d.y; hv[14]=d.z;  hv[15]=d.w;
    }
    float msg[IH];
#pragma unroll
    for (int o = 0; o < IH; ++o) msg[o] = 0.f;
#pragma unroll
    for (int i = 0; i < HID; ++i) {
        float hi = hv[i];
#pragma unroll
        for (int o = 0; o < IH; ++o) {
            float t = b2[i*IH + o];
#pragma unroll
            for (int h = 0; h < IH; ++h)
                t = fmaf(u[h], w2[h*(HID*IH) + i*IH + o], t);
            msg[o] = fmaf(hi, t, msg[o]);
        }
    }
    size_t pos = (size_t)(offset[dst] + rank[e]) * IH;
    float2* mp = reinterpret_cast<float2*>(msgbuf + pos);
    mp[0] = make_float2(msg[0], msg[1]);
    mp[1] = make_float2(msg[2], msg[3]);
    mp[2] = make_float2(msg[4], msg[5]);
    mp[3] = make_float2(msg[6], msg[7]);
    mp[4] = make_float2(msg[8], msg[9]);
}

// ================= node1: segmented reduce + root + relu =================
__global__ __launch_bounds__(256) void node1_red_k(
    const float* __restrict__ hin, const float* __restrict__ msgbuf,
    const int* __restrict__ offset,
    const float* __restrict__ root, const float* __restrict__ bias,
    float* __restrict__ h2)
{
    int idx = blockIdx.x * 256 + threadIdx.x;
    if (idx >= N_NODES * IH) return;
    int n = idx / IH;
    int o = idx - n * IH;
    int beg = offset[n], end = offset[n + 1];
    float s = bias[o];
    for (int j = beg; j < end; ++j) s += msgbuf[(size_t)j * IH + o];
    const float* hr = hin + (size_t)n * HID;
#pragma unroll
    for (int i = 0; i < HID; ++i) s = fmaf(hr[i], root[i*IH + o], s);
    h2[idx] = fmaxf(s, 0.f);
}

// ================= edge predictor: 1 edge/thread =================
__global__ __launch_bounds__(256) void edge_pred_k(
    const float* __restrict__ h2, const float* __restrict__ ea,
    const int* __restrict__ ei,
    const float* __restrict__ w1, const float* __restrict__ b1,
    const float* __restrict__ w2, const float* __restrict__ b2,
    float* __restrict__ out)
{
    int e = blockIdx.x * 256 + threadIdx.x;
    if (e >= E_EDGES) return;
    int src = ei[e];
    float eav[FE];
    load8(ea + (size_t)e * FE, eav);
    float hv[IH];
    {
        const float2* p = reinterpret_cast<const float2*>(h2 + (size_t)src * IH);
        float2 a = p[0], b = p[1], c = p[2], d = p[3], f = p[4];
        hv[0]=a.x; hv[1]=a.y; hv[2]=b.x; hv[3]=b.y; hv[4]=c.x;
        hv[5]=c.y; hv[6]=d.x; hv[7]=d.y; hv[8]=f.x; hv[9]=f.y;
    }
    float score = b2[0];
#pragma unroll
    for (int j = 0; j < IH; ++j) {
        float s = b1[j];
#pragma unroll
        for (int k = 0; k < FE; ++k) s = fmaf(eav[k], w1[k*IH + j], s);
#pragma unroll
        for (int k = 0; k < IH; ++k) s = fmaf(hv[k], w1[(FE + k)*IH + j], s);
        s = fmaxf(s, 0.f);
        score = fmaf(s, w2[j], score);
    }
    out[e] = score;
}

// ================= fallback (atomic) path =================
__global__ __launch_bounds__(256) void conv0_edge_k(
    const float* __restrict__ x, const float* __restrict__ ea,
    const int* __restrict__ ei,
    const float* __restrict__ w1, const float* __restrict__ b1,
    const float* __restrict__ w2, const float* __restrict__ b2,
    float* __restrict__ agg)
{
    int e = blockIdx.x * 256 + threadIdx.x;
    if (e >= E_EDGES) return;
    int src = ei[e];
    int dst = ei[E_EDGES + e];
    float eav[FE];
    load8(ea + (size_t)e * FE, eav);
    float u[IH];
    edge_mlp(eav, w1, b1, u);
    float xv[FN];
    load8(x + (size_t)src * FN, xv);
    float msg[HID];
#pragma unroll
    for (int o = 0; o < HID; ++o) msg[o] = 0.f;
#pragma unroll
    for (int i = 0; i < FN; ++i) {
        float xi = xv[i];
#pragma unroll
        for (int o = 0; o < HID; ++o) {
            float t = b2[i*HID + o];
#pragma unroll
            for (int h = 0; h < IH; ++h)
                t = fmaf(u[h], w2[h*(FN*HID) + i*HID + o], t);
            msg[o] = fmaf(xi, t, msg[o]);
        }
    }
    float* ap = agg + (size_t)dst * HID;
#pragma unroll
    for (int o = 0; o < HID; ++o) atomicAdd(ap + o, msg[o]);
}

__global__ __launch_bounds__(256) void node0_k(
    const float* __restrict__ x, const float* __restrict__ agg,
    const float* __restrict__ root, const float* __restrict__ bias,
    float* __restrict__ h)
{
    int idx = blockIdx.x * 256 + threadIdx.x;
    if (idx >= N_NODES * HID) return;
    int n = idx >> 4;
    int o = idx & 15;
    float s = agg[idx] + bias[o];
    const float* xr = x + (size_t)n * FN;
#pragma unroll
    for (int i = 0; i < FN; ++i) s = fmaf(xr[i], root[i*HID + o], s);
    h[idx] = fmaxf(s, 0.f);
}

__global__ __launch_bounds__(256) void conv1_edge_k(
    const float* __restrict__ hin, const float* __restrict__ ea,
    const int* __restrict__ ei,
    const float* __restrict__ w1, const float* __restrict__ b1,
    const float* __restrict__ w2, const float* __restrict__ b2,
    float* __restrict__ agg)
{
    int e = blockIdx.x * 256 + threadIdx.x;
    if (e >= E_EDGES) return;
    int src = ei[e];
    int dst = ei[E_EDGES + e];
    float eav[FE];
    load8(ea + (size_t)e * FE, eav);
    float u[IH];
    edge_mlp(eav, w1, b1, u);
    float hv[HID];
    {
        const float4* p = reinterpret_cast<const float4*>(hin + (size_t)src * HID);
        float4 a = p[0], b = p[1], c = p[2], d = p[3];
        hv[0]=a.x;  hv[1]=a.y;  hv[2]=a.z;   hv[3]=a.w;
        hv[4]=b.x;  hv[5]=b.y;  hv[6]=b.z;   hv[7]=b.w;
        hv[8]=c.x;  hv[9]=c.y;  hv[10]=c.z;  hv[11]=c.w;
        hv[12]=d.x; hv[13]=d.y; hv[14]=d.z;  hv[15]=d.w;
    }
    float msg[IH];
#pragma unroll
    for (int o = 0; o < IH; ++o) msg[o] = 0.f;
#pragma unroll
    for (int i = 0; i < HID; ++i) {
        float hi = hv[i];
#pragma unroll
        for (int o = 0; o < IH; ++o) {
            float t = b2[i*IH + o];
#pragma unroll
            for (int h = 0; h < IH; ++h)
                t = fmaf(u[h], w2[h*(HID*IH) + i*IH + o], t);
            msg[o] = fmaf(hi, t, msg[o]);
        }
    }
    float* ap = agg + (size_t)dst * IH;
#pragma unroll
    for (int o = 0; o < IH; ++o) atomicAdd(ap + o, msg[o]);
}

__global__ __launch_bounds__(256) void node1_k(
    const float* __restrict__ hin, const float* __restrict__ agg,
    const float* __restrict__ root, const float* __restrict__ bias,
    float* __restrict__ h2)
{
    int idx = blockIdx.x * 256 + threadIdx.x;
    if (idx >= N_NODES * IH) return;
    int n = idx / IH;
    int o = idx - n * IH;
    float s = agg[idx] + bias[o];
    const float* hr = hin + (size_t)n * HID;
#pragma unroll
    for (int i = 0; i < HID; ++i) s = fmaf(hr[i], root[i*IH + o], s);
    h2[idx] = fmaxf(s, 0.f);
}

extern "C" void kernel_launch(void* const* d_in, const int* in_sizes, int n_in,
                              void* d_out, int out_size, void* d_ws, size_t ws_size,
                              hipStream_t stream) {
    const float* x       = (const float*)d_in[0];
    const float* ea      = (const float*)d_in[1];
    const int*   ei      = (const int*)  d_in[2];
    const float* c0_w1   = (const float*)d_in[3];
    const float* c0_b1   = (const float*)d_in[4];
    const float* c0_w2   = (const float*)d_in[5];
    const float* c0_b2   = (const float*)d_in[6];
    const float* c0_root = (const float*)d_in[7];
    const float* c0_bias = (const float*)d_in[8];
    const float* c1_w1   = (const float*)d_in[9];
    const float* c1_b1   = (const float*)d_in[10];
    const float* c1_w2   = (const float*)d_in[11];
    const float* c1_b2   = (const float*)d_in[12];
    const float* c1_root = (const float*)d_in[13];
    const float* c1_bias = (const float*)d_in[14];
    const float* ep_w1   = (const float*)d_in[15];
    const float* ep_b1   = (const float*)d_in[16];
    const float* ep_w2   = (const float*)d_in[17];
    const float* ep_b2   = (const float*)d_in[18];
    float* out = (float*)d_out;

    int eb = (E_EDGES + 255) / 256;

    if (ws_size >= WS_NEED) {
        int*   wi     = (int*)d_ws;
        int*   cnt    = wi + I_CNT;
        int*   offset = wi + I_OFF;
        int*   rank   = wi + I_RANK;
        int*   bsum   = wi + I_BSUM;
        int*   bbase  = wi + I_BBASE;
        float* wf     = (float*)(wi + I_TOTAL);
        float* h      = wf + F_H;
        float* h2     = wf + F_H2;
        float* msg    = wf + F_MSG;

        hipMemsetAsync(cnt, 0, N_NODES * sizeof(int), stream);
        count_rank_k<<<eb, 256, 0, stream>>>(ei, cnt, rank);
        blocksum_k<<<NB_SCAN, 256, 0, stream>>>(cnt, bsum);
        scan_bsums_k<<<1, 256, 0, stream>>>(bsum, bbase);
        offsets_k<<<NB_SCAN, 256, 0, stream>>>(cnt, bbase, offset);

        conv0_scatter_k<<<eb, 256, 0, stream>>>(x, ea, ei, c0_w1, c0_b1, c0_w2, c0_b2,
                                                offset, rank, msg);
        node0_red_k<<<(N_NODES*HID + 255)/256, 256, 0, stream>>>(x, msg, offset,
                                                                 c0_root, c0_bias, h);
        conv1_scatter_k<<<eb, 256, 0, stream>>>(h, ea, ei, c1_w1, c1_b1, c1_w2, c1_b2,
                                                offset, rank, msg);
        node1_red_k<<<(N_NODES*IH + 255)/256, 256, 0, stream>>>(h, msg, offset,
                                                                c1_root, c1_bias, h2);
        edge_pred_k<<<eb, 256, 0, stream>>>(h2, ea, ei, ep_w1, ep_b1, ep_w2, ep_b2, out);
    } else {
        float* ws   = (float*)d_ws;
        float* agg0 = ws;
        float* agg1 = ws + 800000;
        float* h    = ws + 1300000;
        float* h2   = ws + 2100000;
        hipMemsetAsync(d_ws, 0, 1300000 * sizeof(float), stream);
        conv0_edge_k<<<eb, 256, 0, stream>>>(x, ea, ei, c0_w1, c0_b1, c0_w2, c0_b2, agg0);
        node0_k<<<(N_NODES*HID + 255)/256, 256, 0, stream>>>(x, agg0, c0_root, c0_bias, h);
        conv1_edge_k<<<eb, 256, 0, stream>>>(h, ea, ei, c1_w1, c1_b1, c1_w2, c1_b2, agg1);
        node1_k<<<(N_NODES*IH + 255)/256, 256, 0, stream>>>(h, agg1, c1_root, c1_bias, h2);
        edge_pred_k<<<eb, 256, 0, stream>>>(h2, ea, ei, ep_w1, ep_b1, ep_w2, ep_b2, out);
    }
}